// Round 10
// baseline (836.293 us; speedup 1.0000x reference)
//
// R10: DIAGNOSTIC ROUND. Green pipeline byte-identical (guaranteed pass).
// Adds: attn_t14 shadow (T14 split variant -> ob2) + cmp_kern which spins
// ~250us iff ob2 != ob. Reads the rocprof table as the answer channel.
#include <hip/hip_runtime.h>

#define NB 4
#define NS 2048
#define ND 512
#define NH 8
#define NHD 64
#define NM (NB*NS)   // 8192 rows

using bf16 = __bf16;
using bf16x8 = __bf16 __attribute__((ext_vector_type(8)));
using f32x4 = float __attribute__((ext_vector_type(4)));
using i16x4 = short __attribute__((ext_vector_type(4)));

static_assert(sizeof(bf16x8) == 16, "bf16x8 must be 16B");
static_assert(sizeof(i16x4) == 8, "i16x4 must be 8B");

typedef __attribute__((address_space(1))) void glob_t;
typedef __attribute__((address_space(3))) void lds_t;

// v_mfma_f32_16x16x16_bf16: A,B = 2 VGPRs (4 bf16), C/D = 4 VGPRs.
// A: row=lane&15, k=(lane>>4)*4+j ; B: col=lane&15, k=(lane>>4)*4+j
// D: col=lane&15, row=(lane>>4)*4+reg
__device__ __forceinline__ void mfma16(f32x4& c, i16x4 a, i16x4 b) {
    asm("v_mfma_f32_16x16x16_bf16 %0, %1, %2, %0" : "+v"(c) : "v"(a), "v"(b));
}

// ---------------------------------------------------------------------------
// Shared GEMM body: Y = A @ W^T + bias. Tile 128x128, BK=32, 4 waves (2x2).
// (R6-green form, single-buffered.)
// ---------------------------------------------------------------------------
__device__ __forceinline__ void stage16_f32(const float* __restrict__ src, bf16* dst) {
    float4 f0 = *(const float4*)(src + 0);
    float4 f1 = *(const float4*)(src + 4);
    float4 f2 = *(const float4*)(src + 8);
    float4 f3 = *(const float4*)(src + 12);
    bf16x8 v0, v1;
    v0[0]=(bf16)f0.x; v0[1]=(bf16)f0.y; v0[2]=(bf16)f0.z; v0[3]=(bf16)f0.w;
    v0[4]=(bf16)f1.x; v0[5]=(bf16)f1.y; v0[6]=(bf16)f1.z; v0[7]=(bf16)f1.w;
    v1[0]=(bf16)f2.x; v1[1]=(bf16)f2.y; v1[2]=(bf16)f2.z; v1[3]=(bf16)f2.w;
    v1[4]=(bf16)f3.x; v1[5]=(bf16)f3.y; v1[6]=(bf16)f3.z; v1[7]=(bf16)f3.w;
    *(bf16x8*)dst       = v0;
    *(bf16x8*)(dst + 8) = v1;
}

template<bool A_BF16, bool HEAD_OUT>
__device__ __forceinline__ void gemm_body(bf16* As, bf16* Bs, const void* __restrict__ Ap,
        const float* __restrict__ W, const float* __restrict__ bias, void* __restrict__ outp)
{
    constexpr int LP = 40;   // LDS pitch in bf16 elements (80 B rows)
    const int tid  = threadIdx.x;
    const int lane = tid & 63;
    const int wid  = tid >> 6;
    const int wm = wid >> 1, wn = wid & 1;
    const int lr = lane & 15, lg = lane >> 4;
    const int m0 = blockIdx.x * 128, n0 = blockIdx.y * 128;

    const int srow = tid >> 1;            // 0..127
    const int scol = (tid & 1) << 4;      // 0 or 16

    f32x4 acc[4][4] = {};

    for (int k0 = 0; k0 < ND; k0 += 32) {
        if (A_BF16) {
            const bf16* src = (const bf16*)Ap + (size_t)(m0 + srow) * ND + k0 + scol;
            *(uint4*)&As[srow * LP + scol]     = *(const uint4*)(src);
            *(uint4*)&As[srow * LP + scol + 8] = *(const uint4*)(src + 8);
        } else {
            const float* src = (const float*)Ap + (size_t)(m0 + srow) * ND + k0 + scol;
            stage16_f32(src, &As[srow * LP + scol]);
        }
        {
            const float* src = W + (size_t)(n0 + srow) * ND + k0 + scol;
            stage16_f32(src, &Bs[srow * LP + scol]);
        }
        __syncthreads();

        bf16x8 af[4], bfr[4];
        #pragma unroll
        for (int i = 0; i < 4; i++)
            af[i] = *(const bf16x8*)&As[(wm * 64 + i * 16 + lr) * LP + lg * 8];
        #pragma unroll
        for (int i = 0; i < 4; i++)
            bfr[i] = *(const bf16x8*)&Bs[(wn * 64 + i * 16 + lr) * LP + lg * 8];

        #pragma unroll
        for (int mf = 0; mf < 4; mf++)
            #pragma unroll
            for (int nf = 0; nf < 4; nf++)
                acc[mf][nf] = __builtin_amdgcn_mfma_f32_16x16x32_bf16(
                        af[mf], bfr[nf], acc[mf][nf], 0, 0, 0);
        __syncthreads();
    }

    float bv[4];
    #pragma unroll
    for (int nf = 0; nf < 4; nf++)
        bv[nf] = bias[n0 + wn * 64 + nf * 16 + lr];

    #pragma unroll
    for (int mf = 0; mf < 4; mf++) {
        #pragma unroll
        for (int nf = 0; nf < 4; nf++) {
            const int col = n0 + wn * 64 + nf * 16 + lr;
            #pragma unroll
            for (int r = 0; r < 4; r++) {
                const int row = m0 + wm * 64 + mf * 16 + lg * 4 + r;
                const float v = acc[mf][nf][r] + bv[nf];
                if (HEAD_OUT) {
                    const int b  = row >> 11;
                    const int s  = row & (NS - 1);
                    const int hh = col >> 6;
                    const int hd = col & (NHD - 1);
                    ((bf16*)outp)[(((size_t)b * NH + hh) * NS + s) * NHD + hd] = (bf16)v;
                } else {
                    ((float*)outp)[(size_t)row * ND + col] = v;
                }
            }
        }
    }
}

// Batched Q/K/V projection: grid (64, 4, 3)
__global__ __launch_bounds__(256) void gemm_proj3(
        const float* __restrict__ q, const float* __restrict__ k, const float* __restrict__ v,
        const float* __restrict__ wq, const float* __restrict__ wk, const float* __restrict__ wv,
        const float* __restrict__ bq, const float* __restrict__ bk, const float* __restrict__ bv,
        bf16* __restrict__ qb, bf16* __restrict__ kb, bf16* __restrict__ vb)
{
    __shared__ __align__(16) bf16 As[128 * 40];
    __shared__ __align__(16) bf16 Bs[128 * 40];
    const int z = blockIdx.z;
    const float* A = (z == 0) ? q  : (z == 1) ? k  : v;
    const float* W = (z == 0) ? wq : (z == 1) ? wk : wv;
    const float* B = (z == 0) ? bq : (z == 1) ? bk : bv;
    bf16*        o = (z == 0) ? qb : (z == 1) ? kb : vb;
    gemm_body<false, true>(As, Bs, A, W, B, o);
}

// Output projection
__global__ __launch_bounds__(256) void gemm_out(const bf16* __restrict__ A,
        const float* __restrict__ W, const float* __restrict__ b, float* __restrict__ out)
{
    __shared__ __align__(16) bf16 As[128 * 40];
    __shared__ __align__(16) bf16 Bs[128 * 40];
    gemm_body<true, false>(As, Bs, A, W, b, out);
}

// ---------------------------------------------------------------------------
// GREEN flash attention (byte-identical to R6-green).
// ---------------------------------------------------------------------------
#define QSCALE 0.18033688011112042f   // log2(e) / sqrt(64)

__global__ __launch_bounds__(128) void attn_kern(const bf16* __restrict__ Qg,
        const bf16* __restrict__ Kg, const bf16* __restrict__ Vg,
        bf16* __restrict__ Og)
{
    __shared__ __align__(16) bf16 Kt[2][64 * 64];    // [kv][hd], 16B-chunk swizzled
    __shared__ __align__(16) bf16 Vt[2][64 * 64];    // [hd][kv] transposed, swizzled

    const int b = blockIdx.z, h = blockIdx.y;
    const int x = blockIdx.x;
    // heavy/light interleave: 31,0,30,1,... -> uniform per-CU load
    const int qb = (x & 1) ? ((x - 1) >> 1) : (31 - (x >> 1));
    const int tid = threadIdx.x;
    const int lane = tid & 63, w = tid >> 6;
    const int lr = lane & 15, lg = lane >> 4;

    const size_t bh = ((size_t)b * NH + h) * NS;
    const bf16* Kb = Kg + bh * NHD;
    const bf16* Vb = Vg + bh * NHD;

    // ---- K staging source offsets (inverse-swizzled), 4 chunks/thread
    int ksrc[4];
    #pragma unroll
    for (int j = 0; j < 4; j++) {
        const int c   = (w * 4 + j) * 64 + lane;     // 16B chunk 0..511
        const int row = c >> 3;
        const int cs  = (c & 7) ^ (row & 7);
        ksrc[j] = row * NHD + cs * 8;                // bf16 elems
    }

    // ---- V staging mapping: thread -> (hd octet, 4 kv rows)
    const int c8 = tid >> 4;          // 0..7
    const int r0 = (tid & 15) * 4;    // kv row 0..60

    // ---- Q fragments (pre-scaled into log2 domain)
    bf16x8 qf[2][2];
    #pragma unroll
    for (int rf = 0; rf < 2; rf++) {
        const bf16* qp = Qg + (bh + qb * 64 + w * 32 + rf * 16 + lr) * NHD;
        #pragma unroll
        for (int kk = 0; kk < 2; kk++) {
            bf16x8 t = *(const bf16x8*)(qp + kk * 32 + lg * 8);
            #pragma unroll
            for (int j = 0; j < 8; j++)
                qf[rf][kk][j] = (bf16)((float)t[j] * QSCALE);
        }
    }

    f32x4 acc_o[2][4] = {};           // [rf][hf]; lane: q=rf*16+lg*4+rr, hd=hf*16+lr
    float l_lane[2] = {0.f, 0.f};     // per rf; lane's q = lr

    const int qrow0 = qb * 64 + w * 32;
    const int ntiles = qb + 1;

    // ---- staging helpers
    auto stage = [&](int buf, int kv0) {
        #pragma unroll
        for (int j = 0; j < 4; j++)
            __builtin_amdgcn_global_load_lds(
                (const glob_t*)(Kb + (size_t)kv0 * NHD + ksrc[j]),
                (lds_t*)(&Kt[buf][(w * 4 + j) * 512]), 16, 0, 0);
        // V: load 4 rows x 8 hd, transpose-pack to Vt[hd][kv] (swizzled)
        bf16x8 vv[4];
        #pragma unroll
        for (int i = 0; i < 4; i++)
            vv[i] = *(const bf16x8*)(Vb + (size_t)(kv0 + r0 + i) * NHD + c8 * 8);
        #pragma unroll
        for (int j = 0; j < 8; j++) {
            const int hd = c8 * 8 + j;
            int byte = hd * 128 + r0 * 2;
            byte ^= (hd & 7) << 4;
            i16x4 pk;
            #pragma unroll
            for (int i = 0; i < 4; i++) {
                bf16 hval = vv[i][j];
                pk[i] = (short)__builtin_bit_cast(unsigned short, hval);
            }
            *(i16x4*)((char*)&Vt[buf][0] + byte) = pk;
        }
    };

    stage(0, 0);
    __syncthreads();

    int cur = 0;
    for (int t = 0; t < ntiles; t++) {
        const int kv0 = t * 64;
        if (t + 1 < ntiles) stage(cur ^ 1, kv0 + 64);

        // ---- S^T = K Q^T (log2 domain): s[nf][rf], lane q=lr, kv=nf*16+lg*4+rr
        f32x4 s[4][2];
        #pragma unroll
        for (int nf = 0; nf < 4; nf++) {
            bf16x8 kf[2];
            #pragma unroll
            for (int kk = 0; kk < 2; kk++) {
                const int row = nf * 16 + lr;
                int byte = row * 128 + (kk * 32 + lg * 8) * 2;
                byte ^= (row & 7) << 4;
                kf[kk] = *(const bf16x8*)((const char*)&Kt[cur][0] + byte);
            }
            #pragma unroll
            for (int rf = 0; rf < 2; rf++) {
                f32x4 a = {};
                a = __builtin_amdgcn_mfma_f32_16x16x32_bf16(kf[0], qf[rf][0], a, 0, 0, 0);
                a = __builtin_amdgcn_mfma_f32_16x16x32_bf16(kf[1], qf[rf][1], a, 0, 0, 0);
                s[nf][rf] = a;
            }
        }

        // ---- p = exp2(s); P stays in registers as x16-MFMA A-fragments
        i16x4 pa[2][4];   // [rf][nf]
        if (kv0 + 63 > qrow0) {         // diagonal region: apply causal mask
            #pragma unroll
            for (int rf = 0; rf < 2; rf++) {
                const int qg = qrow0 + rf * 16 + lr;
                #pragma unroll
                for (int nf = 0; nf < 4; nf++)
                    #pragma unroll
                    for (int rr = 0; rr < 4; rr++) {
                        const int kvg = kv0 + nf * 16 + lg * 4 + rr;
                        float sv = s[nf][rf][rr];
                        sv = (kvg > qg) ? -1e30f : sv;
                        const float p = __builtin_amdgcn_exp2f(sv);
                        l_lane[rf] += p;
                        bf16 ph = (bf16)p;
                        pa[rf][nf][rr] = (short)__builtin_bit_cast(unsigned short, ph);
                    }
            }
        } else {
            #pragma unroll
            for (int rf = 0; rf < 2; rf++)
                #pragma unroll
                for (int nf = 0; nf < 4; nf++)
                    #pragma unroll
                    for (int rr = 0; rr < 4; rr++) {
                        const float p = __builtin_amdgcn_exp2f(s[nf][rf][rr]);
                        l_lane[rf] += p;
                        bf16 ph = (bf16)p;
                        pa[rf][nf][rr] = (short)__builtin_bit_cast(unsigned short, ph);
                    }
        }

        // ---- V^T fragments (b64, swizzled: 2-way conflicts only) + PV
        i16x4 vf[4][4];   // [hf][nf]: lane hd=hf*16+lr, kv=nf*16+lg*4+j
        #pragma unroll
        for (int hf = 0; hf < 4; hf++)
            #pragma unroll
            for (int nf = 0; nf < 4; nf++) {
                const int hd = hf * 16 + lr;
                int byte = hd * 128 + (nf * 16 + lg * 4) * 2;
                byte ^= (hd & 7) << 4;
                vf[hf][nf] = *(const i16x4*)((const char*)&Vt[cur][0] + byte);
            }

        __builtin_amdgcn_s_setprio(1);
        #pragma unroll
        for (int rf = 0; rf < 2; rf++)
            #pragma unroll
            for (int hf = 0; hf < 4; hf++)
                #pragma unroll
                for (int nf = 0; nf < 4; nf++)
                    mfma16(acc_o[rf][hf], pa[rf][nf], vf[hf][nf]);
        __builtin_amdgcn_s_setprio(0);

        __syncthreads();     // drains global_load_lds (vmcnt) + V ds_writes
        cur ^= 1;
    }

    // ---- epilogue: reduce l across lane groups, normalize, store
    #pragma unroll
    for (int rf = 0; rf < 2; rf++) {
        float l = l_lane[rf];
        l += __shfl_xor(l, 16);
        l += __shfl_xor(l, 32);
        const float linv = 1.0f / l;
        #pragma unroll
        for (int rr = 0; rr < 4; rr++) {
            const float li = __shfl(linv, lg * 4 + rr, 16);
            const int row = qrow0 + rf * 16 + lg * 4 + rr;
            #pragma unroll
            for (int hf = 0; hf < 4; hf++) {
                const int col = h * NHD + hf * 16 + lr;
                Og[((size_t)b * NS + row) * ND + col] = (bf16)(acc_o[rf][hf][rr] * li);
            }
        }
    }
}

// ---------------------------------------------------------------------------
// SHADOW: T14-split variant (the R9 kernel), writes to ob2 only.
// ---------------------------------------------------------------------------
__global__ __launch_bounds__(128) void attn_t14(const bf16* __restrict__ Qg,
        const bf16* __restrict__ Kg, const bf16* __restrict__ Vg,
        bf16* __restrict__ Og)
{
    __shared__ __align__(16) bf16 Kt[2][64 * 64];
    __shared__ __align__(16) bf16 Vt[2][64 * 64];

    const int b = blockIdx.z, h = blockIdx.y;
    const int x = blockIdx.x;
    const int qb = (x & 1) ? ((x - 1) >> 1) : (31 - (x >> 1));
    const int tid = threadIdx.x;
    const int lane = tid & 63, w = tid >> 6;
    const int lr = lane & 15, lg = lane >> 4;

    const size_t bh = ((size_t)b * NH + h) * NS;
    const bf16* Kb = Kg + bh * NHD;
    const bf16* Vb = Vg + bh * NHD;

    int ksrc[4];
    #pragma unroll
    for (int j = 0; j < 4; j++) {
        const int c   = (w * 4 + j) * 64 + lane;
        const int row = c >> 3;
        const int cs  = (c & 7) ^ (row & 7);
        ksrc[j] = row * NHD + cs * 8;
    }

    const int c8 = tid >> 4;
    const int r0 = (tid & 15) * 4;

    bf16x8 qf[2][2];
    #pragma unroll
    for (int rf = 0; rf < 2; rf++) {
        const bf16* qp = Qg + (bh + qb * 64 + w * 32 + rf * 16 + lr) * NHD;
        #pragma unroll
        for (int kk = 0; kk < 2; kk++) {
            bf16x8 t = *(const bf16x8*)(qp + kk * 32 + lg * 8);
            #pragma unroll
            for (int j = 0; j < 8; j++)
                qf[rf][kk][j] = (bf16)((float)t[j] * QSCALE);
        }
    }

    f32x4 acc_o[2][4] = {};
    float l_lane[2] = {0.f, 0.f};

    const int qrow0 = qb * 64 + w * 32;
    const int ntiles = qb + 1;

    auto k_issue = [&](int buf, int kv0) {
        #pragma unroll
        for (int j = 0; j < 4; j++)
            __builtin_amdgcn_global_load_lds(
                (const glob_t*)(Kb + (size_t)kv0 * NHD + ksrc[j]),
                (lds_t*)(&Kt[buf][(w * 4 + j) * 512]), 16, 0, 0);
    };
    auto v_load = [&](bf16x8* vv, int kv0) {
        #pragma unroll
        for (int i = 0; i < 4; i++)
            vv[i] = *(const bf16x8*)(Vb + (size_t)(kv0 + r0 + i) * NHD + c8 * 8);
    };
    auto v_write = [&](int buf, const bf16x8* vv) {
        #pragma unroll
        for (int j = 0; j < 8; j++) {
            const int hd = c8 * 8 + j;
            int byte = hd * 128 + r0 * 2;
            byte ^= (hd & 7) << 4;
            i16x4 pk;
            #pragma unroll
            for (int i = 0; i < 4; i++)
                pk[i] = (short)__builtin_bit_cast(unsigned short, vv[i][j]);
            *(i16x4*)((char*)&Vt[buf][0] + byte) = pk;
        }
    };

    {
        bf16x8 v0[4];
        k_issue(0, 0);
        v_load(v0, 0);
        v_write(0, v0);
    }
    __syncthreads();

    int cur = 0;
    for (int t = 0; t < ntiles; t++) {
        const int kv0 = t * 64;
        const bool have_next = (t + 1 < ntiles);
        bf16x8 vnxt[4];
        if (have_next) {
            k_issue(cur ^ 1, kv0 + 64);
            v_load(vnxt, kv0 + 64);
        }

        f32x4 s[4][2];
        #pragma unroll
        for (int nf = 0; nf < 4; nf++) {
            bf16x8 kf[2];
            #pragma unroll
            for (int kk = 0; kk < 2; kk++) {
                const int row = nf * 16 + lr;
                int byte = row * 128 + (kk * 32 + lg * 8) * 2;
                byte ^= (row & 7) << 4;
                kf[kk] = *(const bf16x8*)((const char*)&Kt[cur][0] + byte);
            }
            #pragma unroll
            for (int rf = 0; rf < 2; rf++) {
                f32x4 a = {};
                a = __builtin_amdgcn_mfma_f32_16x16x32_bf16(kf[0], qf[rf][0], a, 0, 0, 0);
                a = __builtin_amdgcn_mfma_f32_16x16x32_bf16(kf[1], qf[rf][1], a, 0, 0, 0);
                s[nf][rf] = a;
            }
        }

        i16x4 pa[2][4];
        if (kv0 + 63 > qrow0) {
            #pragma unroll
            for (int rf = 0; rf < 2; rf++) {
                const int qg = qrow0 + rf * 16 + lr;
                #pragma unroll
                for (int nf = 0; nf < 4; nf++)
                    #pragma unroll
                    for (int rr = 0; rr < 4; rr++) {
                        const int kvg = kv0 + nf * 16 + lg * 4 + rr;
                        float sv = s[nf][rf][rr];
                        sv = (kvg > qg) ? -1e30f : sv;
                        const float p = __builtin_amdgcn_exp2f(sv);
                        l_lane[rf] += p;
                        bf16 ph = (bf16)p;
                        pa[rf][nf][rr] = (short)__builtin_bit_cast(unsigned short, ph);
                    }
            }
        } else {
            #pragma unroll
            for (int rf = 0; rf < 2; rf++)
                #pragma unroll
                for (int nf = 0; nf < 4; nf++)
                    #pragma unroll
                    for (int rr = 0; rr < 4; rr++) {
                        const float p = __builtin_amdgcn_exp2f(s[nf][rf][rr]);
                        l_lane[rf] += p;
                        bf16 ph = (bf16)p;
                        pa[rf][nf][rr] = (short)__builtin_bit_cast(unsigned short, ph);
                    }
        }

        i16x4 vf[4][4];
        #pragma unroll
        for (int hf = 0; hf < 4; hf++)
            #pragma unroll
            for (int nf = 0; nf < 4; nf++) {
                const int hd = hf * 16 + lr;
                int byte = hd * 128 + (nf * 16 + lg * 4) * 2;
                byte ^= (hd & 7) << 4;
                vf[hf][nf] = *(const i16x4*)((const char*)&Vt[cur][0] + byte);
            }

        __builtin_amdgcn_s_setprio(1);
        #pragma unroll
        for (int rf = 0; rf < 2; rf++)
            #pragma unroll
            for (int hf = 0; hf < 4; hf++)
                #pragma unroll
                for (int nf = 0; nf < 4; nf++)
                    mfma16(acc_o[rf][hf], pa[rf][nf], vf[hf][nf]);
        __builtin_amdgcn_s_setprio(0);

        if (have_next)
            v_write(cur ^ 1, vnxt);
        __syncthreads();
        cur ^= 1;
    }

    #pragma unroll
    for (int rf = 0; rf < 2; rf++) {
        float l = l_lane[rf];
        l += __shfl_xor(l, 16);
        l += __shfl_xor(l, 32);
        const float linv = 1.0f / l;
        #pragma unroll
        for (int rr = 0; rr < 4; rr++) {
            const float li = __shfl(linv, lg * 4 + rr, 16);
            const int row = qrow0 + rf * 16 + lg * 4 + rr;
            #pragma unroll
            for (int hf = 0; hf < 4; hf++) {
                const int col = h * NHD + hf * 16 + lr;
                Og[((size_t)b * NS + row) * ND + col] = (bf16)(acc_o[rf][hf][rr] * li);
            }
        }
    }
}

// ---------------------------------------------------------------------------
// Compare: spins ~250us iff any |ob - ob2| > 1e-3. Duration = answer channel.
// ---------------------------------------------------------------------------
__global__ __launch_bounds__(256) void cmp_kern(const bf16* __restrict__ a,
                                                const bf16* __restrict__ b)
{
    const size_t n = (size_t)NM * ND;
    float md = 0.f;
    for (size_t i = (size_t)blockIdx.x * 256 + threadIdx.x; i < n; i += (size_t)256 * 1024)
        md = fmaxf(md, fabsf((float)a[i] - (float)b[i]));
    #pragma unroll
    for (int off = 1; off < 64; off <<= 1)
        md = fmaxf(md, __shfl_xor(md, off));
    if (md > 1e-3f) {
        float xx = md;
        for (int i = 0; i < 150000; i++)
            asm volatile("v_fma_f32 %0, %0, %1, %2" : "+v"(xx) : "v"(1.0000001f), "v"(1e-7f));
        asm volatile("" :: "v"(xx));   // keep live (rule #17)
    }
}

// ---------------------------------------------------------------------------
extern "C" void kernel_launch(void* const* d_in, const int* in_sizes, int n_in,
                              void* d_out, int out_size, void* d_ws, size_t ws_size,
                              hipStream_t stream) {
    const float* query = (const float*)d_in[0];
    const float* key   = (const float*)d_in[1];
    const float* value = (const float*)d_in[2];
    // d_in[3] = mask: causal tril by construction -> computed analytically
    const float* wq = (const float*)d_in[4];
    const float* bq = (const float*)d_in[5];
    const float* wk = (const float*)d_in[6];
    const float* bk = (const float*)d_in[7];
    const float* wv = (const float*)d_in[8];
    const float* bv = (const float*)d_in[9];
    const float* wo = (const float*)d_in[10];
    const float* bo = (const float*)d_in[11];
    float* out = (float*)d_out;

    bf16* qb  = (bf16*)d_ws;                       // (B,H,S,HD)
    bf16* kb  = qb + (size_t)NM * ND;
    bf16* vb  = kb + (size_t)NM * ND;
    bf16* ob  = vb + (size_t)NM * ND;              // (B,S,D)
    bf16* ob2 = ob + (size_t)NM * ND;              // shadow output

    const bool do_shadow = ws_size >= (size_t)5 * NM * ND * sizeof(bf16);

    gemm_proj3<<<dim3(NM / 128, ND / 128, 3), 256, 0, stream>>>(
            query, key, value, wq, wk, wv, bq, bk, bv, qb, kb, vb);

    attn_kern<<<dim3(NS / 64, NH, NB), 128, 0, stream>>>(qb, kb, vb, ob);

    if (do_shadow) {
        attn_t14<<<dim3(NS / 64, NH, NB), 128, 0, stream>>>(qb, kb, vb, ob2);
        cmp_kern<<<dim3(1024), 256, 0, stream>>>(ob, ob2);
    }

    gemm_out<<<dim3(NM / 128, ND / 128), 256, 0, stream>>>(ob, wo, bo, out);
}

// Round 11
// 828.169 us; speedup vs baseline: 1.0098x; 1.0098x over previous
//
// R11: DIAGNOSTIC ROUND 2. Green pipeline byte-identical (guaranteed pass).
// Shadow attn_v2: conservative rewrite -- NO global_load_lds, NO double-buffer,
// single K/V LDS buffer, reg-staged 2-barrier protocol, complementary-pair
// load balance (each block: qb = a then 31-a -> exactly 33 tile-iters).
// cmp_kern spins ~750us iff attn_v2 output != green output.
#include <hip/hip_runtime.h>

#define NB 4
#define NS 2048
#define ND 512
#define NH 8
#define NHD 64
#define NM (NB*NS)   // 8192 rows

using bf16 = __bf16;
using bf16x8 = __bf16 __attribute__((ext_vector_type(8)));
using f32x4 = float __attribute__((ext_vector_type(4)));
using i16x4 = short __attribute__((ext_vector_type(4)));

static_assert(sizeof(bf16x8) == 16, "bf16x8 must be 16B");
static_assert(sizeof(i16x4) == 8, "i16x4 must be 8B");

typedef __attribute__((address_space(1))) void glob_t;
typedef __attribute__((address_space(3))) void lds_t;

// v_mfma_f32_16x16x16_bf16: A,B = 2 VGPRs (4 bf16), C/D = 4 VGPRs.
// A: row=lane&15, k=(lane>>4)*4+j ; B: col=lane&15, k=(lane>>4)*4+j
// D: col=lane&15, row=(lane>>4)*4+reg
__device__ __forceinline__ void mfma16(f32x4& c, i16x4 a, i16x4 b) {
    asm("v_mfma_f32_16x16x16_bf16 %0, %1, %2, %0" : "+v"(c) : "v"(a), "v"(b));
}

// ---------------------------------------------------------------------------
// Shared GEMM body: Y = A @ W^T + bias. Tile 128x128, BK=32, 4 waves (2x2).
// (R6-green form, single-buffered.)
// ---------------------------------------------------------------------------
__device__ __forceinline__ void stage16_f32(const float* __restrict__ src, bf16* dst) {
    float4 f0 = *(const float4*)(src + 0);
    float4 f1 = *(const float4*)(src + 4);
    float4 f2 = *(const float4*)(src + 8);
    float4 f3 = *(const float4*)(src + 12);
    bf16x8 v0, v1;
    v0[0]=(bf16)f0.x; v0[1]=(bf16)f0.y; v0[2]=(bf16)f0.z; v0[3]=(bf16)f0.w;
    v0[4]=(bf16)f1.x; v0[5]=(bf16)f1.y; v0[6]=(bf16)f1.z; v0[7]=(bf16)f1.w;
    v1[0]=(bf16)f2.x; v1[1]=(bf16)f2.y; v1[2]=(bf16)f2.z; v1[3]=(bf16)f2.w;
    v1[4]=(bf16)f3.x; v1[5]=(bf16)f3.y; v1[6]=(bf16)f3.z; v1[7]=(bf16)f3.w;
    *(bf16x8*)dst       = v0;
    *(bf16x8*)(dst + 8) = v1;
}

template<bool A_BF16, bool HEAD_OUT>
__device__ __forceinline__ void gemm_body(bf16* As, bf16* Bs, const void* __restrict__ Ap,
        const float* __restrict__ W, const float* __restrict__ bias, void* __restrict__ outp)
{
    constexpr int LP = 40;   // LDS pitch in bf16 elements (80 B rows)
    const int tid  = threadIdx.x;
    const int lane = tid & 63;
    const int wid  = tid >> 6;
    const int wm = wid >> 1, wn = wid & 1;
    const int lr = lane & 15, lg = lane >> 4;
    const int m0 = blockIdx.x * 128, n0 = blockIdx.y * 128;

    const int srow = tid >> 1;            // 0..127
    const int scol = (tid & 1) << 4;      // 0 or 16

    f32x4 acc[4][4] = {};

    for (int k0 = 0; k0 < ND; k0 += 32) {
        if (A_BF16) {
            const bf16* src = (const bf16*)Ap + (size_t)(m0 + srow) * ND + k0 + scol;
            *(uint4*)&As[srow * LP + scol]     = *(const uint4*)(src);
            *(uint4*)&As[srow * LP + scol + 8] = *(const uint4*)(src + 8);
        } else {
            const float* src = (const float*)Ap + (size_t)(m0 + srow) * ND + k0 + scol;
            stage16_f32(src, &As[srow * LP + scol]);
        }
        {
            const float* src = W + (size_t)(n0 + srow) * ND + k0 + scol;
            stage16_f32(src, &Bs[srow * LP + scol]);
        }
        __syncthreads();

        bf16x8 af[4], bfr[4];
        #pragma unroll
        for (int i = 0; i < 4; i++)
            af[i] = *(const bf16x8*)&As[(wm * 64 + i * 16 + lr) * LP + lg * 8];
        #pragma unroll
        for (int i = 0; i < 4; i++)
            bfr[i] = *(const bf16x8*)&Bs[(wn * 64 + i * 16 + lr) * LP + lg * 8];

        #pragma unroll
        for (int mf = 0; mf < 4; mf++)
            #pragma unroll
            for (int nf = 0; nf < 4; nf++)
                acc[mf][nf] = __builtin_amdgcn_mfma_f32_16x16x32_bf16(
                        af[mf], bfr[nf], acc[mf][nf], 0, 0, 0);
        __syncthreads();
    }

    float bv[4];
    #pragma unroll
    for (int nf = 0; nf < 4; nf++)
        bv[nf] = bias[n0 + wn * 64 + nf * 16 + lr];

    #pragma unroll
    for (int mf = 0; mf < 4; mf++) {
        #pragma unroll
        for (int nf = 0; nf < 4; nf++) {
            const int col = n0 + wn * 64 + nf * 16 + lr;
            #pragma unroll
            for (int r = 0; r < 4; r++) {
                const int row = m0 + wm * 64 + mf * 16 + lg * 4 + r;
                const float v = acc[mf][nf][r] + bv[nf];
                if (HEAD_OUT) {
                    const int b  = row >> 11;
                    const int s  = row & (NS - 1);
                    const int hh = col >> 6;
                    const int hd = col & (NHD - 1);
                    ((bf16*)outp)[(((size_t)b * NH + hh) * NS + s) * NHD + hd] = (bf16)v;
                } else {
                    ((float*)outp)[(size_t)row * ND + col] = v;
                }
            }
        }
    }
}

// Batched Q/K/V projection: grid (64, 4, 3)
__global__ __launch_bounds__(256) void gemm_proj3(
        const float* __restrict__ q, const float* __restrict__ k, const float* __restrict__ v,
        const float* __restrict__ wq, const float* __restrict__ wk, const float* __restrict__ wv,
        const float* __restrict__ bq, const float* __restrict__ bk, const float* __restrict__ bv,
        bf16* __restrict__ qb, bf16* __restrict__ kb, bf16* __restrict__ vb)
{
    __shared__ __align__(16) bf16 As[128 * 40];
    __shared__ __align__(16) bf16 Bs[128 * 40];
    const int z = blockIdx.z;
    const float* A = (z == 0) ? q  : (z == 1) ? k  : v;
    const float* W = (z == 0) ? wq : (z == 1) ? wk : wv;
    const float* B = (z == 0) ? bq : (z == 1) ? bk : bv;
    bf16*        o = (z == 0) ? qb : (z == 1) ? kb : vb;
    gemm_body<false, true>(As, Bs, A, W, B, o);
}

// Output projection
__global__ __launch_bounds__(256) void gemm_out(const bf16* __restrict__ A,
        const float* __restrict__ W, const float* __restrict__ b, float* __restrict__ out)
{
    __shared__ __align__(16) bf16 As[128 * 40];
    __shared__ __align__(16) bf16 Bs[128 * 40];
    gemm_body<true, false>(As, Bs, A, W, b, out);
}

// ---------------------------------------------------------------------------
// GREEN flash attention (byte-identical to R6-green).
// ---------------------------------------------------------------------------
#define QSCALE 0.18033688011112042f   // log2(e) / sqrt(64)

__global__ __launch_bounds__(128) void attn_kern(const bf16* __restrict__ Qg,
        const bf16* __restrict__ Kg, const bf16* __restrict__ Vg,
        bf16* __restrict__ Og)
{
    __shared__ __align__(16) bf16 Kt[2][64 * 64];    // [kv][hd], 16B-chunk swizzled
    __shared__ __align__(16) bf16 Vt[2][64 * 64];    // [hd][kv] transposed, swizzled

    const int b = blockIdx.z, h = blockIdx.y;
    const int x = blockIdx.x;
    // heavy/light interleave: 31,0,30,1,... -> uniform per-CU load
    const int qb = (x & 1) ? ((x - 1) >> 1) : (31 - (x >> 1));
    const int tid = threadIdx.x;
    const int lane = tid & 63, w = tid >> 6;
    const int lr = lane & 15, lg = lane >> 4;

    const size_t bh = ((size_t)b * NH + h) * NS;
    const bf16* Kb = Kg + bh * NHD;
    const bf16* Vb = Vg + bh * NHD;

    // ---- K staging source offsets (inverse-swizzled), 4 chunks/thread
    int ksrc[4];
    #pragma unroll
    for (int j = 0; j < 4; j++) {
        const int c   = (w * 4 + j) * 64 + lane;     // 16B chunk 0..511
        const int row = c >> 3;
        const int cs  = (c & 7) ^ (row & 7);
        ksrc[j] = row * NHD + cs * 8;                // bf16 elems
    }

    // ---- V staging mapping: thread -> (hd octet, 4 kv rows)
    const int c8 = tid >> 4;          // 0..7
    const int r0 = (tid & 15) * 4;    // kv row 0..60

    // ---- Q fragments (pre-scaled into log2 domain)
    bf16x8 qf[2][2];
    #pragma unroll
    for (int rf = 0; rf < 2; rf++) {
        const bf16* qp = Qg + (bh + qb * 64 + w * 32 + rf * 16 + lr) * NHD;
        #pragma unroll
        for (int kk = 0; kk < 2; kk++) {
            bf16x8 t = *(const bf16x8*)(qp + kk * 32 + lg * 8);
            #pragma unroll
            for (int j = 0; j < 8; j++)
                qf[rf][kk][j] = (bf16)((float)t[j] * QSCALE);
        }
    }

    f32x4 acc_o[2][4] = {};           // [rf][hf]; lane: q=rf*16+lg*4+rr, hd=hf*16+lr
    float l_lane[2] = {0.f, 0.f};     // per rf; lane's q = lr

    const int qrow0 = qb * 64 + w * 32;
    const int ntiles = qb + 1;

    // ---- staging helpers
    auto stage = [&](int buf, int kv0) {
        #pragma unroll
        for (int j = 0; j < 4; j++)
            __builtin_amdgcn_global_load_lds(
                (const glob_t*)(Kb + (size_t)kv0 * NHD + ksrc[j]),
                (lds_t*)(&Kt[buf][(w * 4 + j) * 512]), 16, 0, 0);
        // V: load 4 rows x 8 hd, transpose-pack to Vt[hd][kv] (swizzled)
        bf16x8 vv[4];
        #pragma unroll
        for (int i = 0; i < 4; i++)
            vv[i] = *(const bf16x8*)(Vb + (size_t)(kv0 + r0 + i) * NHD + c8 * 8);
        #pragma unroll
        for (int j = 0; j < 8; j++) {
            const int hd = c8 * 8 + j;
            int byte = hd * 128 + r0 * 2;
            byte ^= (hd & 7) << 4;
            i16x4 pk;
            #pragma unroll
            for (int i = 0; i < 4; i++) {
                bf16 hval = vv[i][j];
                pk[i] = (short)__builtin_bit_cast(unsigned short, hval);
            }
            *(i16x4*)((char*)&Vt[buf][0] + byte) = pk;
        }
    };

    stage(0, 0);
    __syncthreads();

    int cur = 0;
    for (int t = 0; t < ntiles; t++) {
        const int kv0 = t * 64;
        if (t + 1 < ntiles) stage(cur ^ 1, kv0 + 64);

        // ---- S^T = K Q^T (log2 domain): s[nf][rf], lane q=lr, kv=nf*16+lg*4+rr
        f32x4 s[4][2];
        #pragma unroll
        for (int nf = 0; nf < 4; nf++) {
            bf16x8 kf[2];
            #pragma unroll
            for (int kk = 0; kk < 2; kk++) {
                const int row = nf * 16 + lr;
                int byte = row * 128 + (kk * 32 + lg * 8) * 2;
                byte ^= (row & 7) << 4;
                kf[kk] = *(const bf16x8*)((const char*)&Kt[cur][0] + byte);
            }
            #pragma unroll
            for (int rf = 0; rf < 2; rf++) {
                f32x4 a = {};
                a = __builtin_amdgcn_mfma_f32_16x16x32_bf16(kf[0], qf[rf][0], a, 0, 0, 0);
                a = __builtin_amdgcn_mfma_f32_16x16x32_bf16(kf[1], qf[rf][1], a, 0, 0, 0);
                s[nf][rf] = a;
            }
        }

        // ---- p = exp2(s); P stays in registers as x16-MFMA A-fragments
        i16x4 pa[2][4];   // [rf][nf]
        if (kv0 + 63 > qrow0) {         // diagonal region: apply causal mask
            #pragma unroll
            for (int rf = 0; rf < 2; rf++) {
                const int qg = qrow0 + rf * 16 + lr;
                #pragma unroll
                for (int nf = 0; nf < 4; nf++)
                    #pragma unroll
                    for (int rr = 0; rr < 4; rr++) {
                        const int kvg = kv0 + nf * 16 + lg * 4 + rr;
                        float sv = s[nf][rf][rr];
                        sv = (kvg > qg) ? -1e30f : sv;
                        const float p = __builtin_amdgcn_exp2f(sv);
                        l_lane[rf] += p;
                        bf16 ph = (bf16)p;
                        pa[rf][nf][rr] = (short)__builtin_bit_cast(unsigned short, ph);
                    }
            }
        } else {
            #pragma unroll
            for (int rf = 0; rf < 2; rf++)
                #pragma unroll
                for (int nf = 0; nf < 4; nf++)
                    #pragma unroll
                    for (int rr = 0; rr < 4; rr++) {
                        const float p = __builtin_amdgcn_exp2f(s[nf][rf][rr]);
                        l_lane[rf] += p;
                        bf16 ph = (bf16)p;
                        pa[rf][nf][rr] = (short)__builtin_bit_cast(unsigned short, ph);
                    }
        }

        // ---- V^T fragments (b64, swizzled: 2-way conflicts only) + PV
        i16x4 vf[4][4];   // [hf][nf]: lane hd=hf*16+lr, kv=nf*16+lg*4+j
        #pragma unroll
        for (int hf = 0; hf < 4; hf++)
            #pragma unroll
            for (int nf = 0; nf < 4; nf++) {
                const int hd = hf * 16 + lr;
                int byte = hd * 128 + (nf * 16 + lg * 4) * 2;
                byte ^= (hd & 7) << 4;
                vf[hf][nf] = *(const i16x4*)((const char*)&Vt[cur][0] + byte);
            }

        __builtin_amdgcn_s_setprio(1);
        #pragma unroll
        for (int rf = 0; rf < 2; rf++)
            #pragma unroll
            for (int hf = 0; hf < 4; hf++)
                #pragma unroll
                for (int nf = 0; nf < 4; nf++)
                    mfma16(acc_o[rf][hf], pa[rf][nf], vf[hf][nf]);
        __builtin_amdgcn_s_setprio(0);

        __syncthreads();     // drains global_load_lds (vmcnt) + V ds_writes
        cur ^= 1;
    }

    // ---- epilogue: reduce l across lane groups, normalize, store
    #pragma unroll
    for (int rf = 0; rf < 2; rf++) {
        float l = l_lane[rf];
        l += __shfl_xor(l, 16);
        l += __shfl_xor(l, 32);
        const float linv = 1.0f / l;
        #pragma unroll
        for (int rr = 0; rr < 4; rr++) {
            const float li = __shfl(linv, lg * 4 + rr, 16);
            const int row = qrow0 + rf * 16 + lg * 4 + rr;
            #pragma unroll
            for (int hf = 0; hf < 4; hf++) {
                const int col = h * NHD + hf * 16 + lr;
                Og[((size_t)b * NS + row) * ND + col] = (bf16)(acc_o[rf][hf][rr] * li);
            }
        }
    }
}

// ---------------------------------------------------------------------------
// SHADOW attn_v2: no global_load_lds, single LDS buffer, 2-barrier reg-staged
// protocol, complementary-pair balance. Writes ob2 only.
// ---------------------------------------------------------------------------
__global__ __launch_bounds__(128) void attn_v2(const bf16* __restrict__ Qg,
        const bf16* __restrict__ Kg, const bf16* __restrict__ Vg,
        bf16* __restrict__ Og)
{
    __shared__ __align__(16) bf16 Kt[64 * 64];    // [kv][hd], chunk-swizzled
    __shared__ __align__(16) bf16 Vt[64 * 64];    // [hd][kv] transposed, swizzled

    const int b = blockIdx.z, h = blockIdx.y;
    const int a = blockIdx.x;                     // 0..15; passes do qb = a, 31-a
    const int tid = threadIdx.x;
    const int lane = tid & 63, w = tid >> 6;
    const int lr = lane & 15, lg = lane >> 4;

    const size_t bh = ((size_t)b * NH + h) * NS;
    const bf16* Kb = Kg + bh * NHD;
    const bf16* Vb = Vg + bh * NHD;

    // V staging mapping (green construct): thread -> (hd octet, 4 kv rows)
    const int c8 = tid >> 4;
    const int r0 = (tid & 15) * 4;

    #pragma unroll 1
    for (int pass = 0; pass < 2; pass++) {
        const int qb = pass ? (31 - a) : a;

        bf16x8 qf[2][2];
        #pragma unroll
        for (int rf = 0; rf < 2; rf++) {
            const bf16* qp = Qg + (bh + qb * 64 + w * 32 + rf * 16 + lr) * NHD;
            #pragma unroll
            for (int kk = 0; kk < 2; kk++) {
                bf16x8 t = *(const bf16x8*)(qp + kk * 32 + lg * 8);
                #pragma unroll
                for (int j = 0; j < 8; j++)
                    qf[rf][kk][j] = (bf16)((float)t[j] * QSCALE);
            }
        }

        f32x4 acc_o[2][4] = {};
        float l_lane[2] = {0.f, 0.f};
        const int qrow0 = qb * 64 + w * 32;
        const int ntiles = qb + 1;

        #pragma unroll 1
        for (int t = 0; t < ntiles; t++) {
            const int kv0 = t * 64;

            // (1) global -> reg (issued before barrier; latency overlaps
            //     the other waves' tail of the previous compute phase)
            bf16x8 kreg[4];
            #pragma unroll
            for (int j = 0; j < 4; j++) {
                const int c = tid * 4 + j;          // 16B chunk 0..511
                const int row = c >> 3, hc = c & 7;
                kreg[j] = *(const bf16x8*)(Kb + (size_t)(kv0 + row) * NHD + hc * 8);
            }
            bf16x8 vreg[4];
            #pragma unroll
            for (int i = 0; i < 4; i++)
                vreg[i] = *(const bf16x8*)(Vb + (size_t)(kv0 + r0 + i) * NHD + c8 * 8);

            __syncthreads();   // all waves finished READING the previous tile

            // (2) reg -> LDS
            #pragma unroll
            for (int j = 0; j < 4; j++) {
                const int c = tid * 4 + j;
                const int row = c >> 3, hc = c & 7;
                const int byte = (row * 128 + hc * 16) ^ ((row & 7) << 4);
                *(bf16x8*)((char*)Kt + byte) = kreg[j];
            }
            #pragma unroll
            for (int j = 0; j < 8; j++) {
                const int hd = c8 * 8 + j;
                int byte = hd * 128 + r0 * 2;
                byte ^= (hd & 7) << 4;
                i16x4 pk;
                #pragma unroll
                for (int i = 0; i < 4; i++)
                    pk[i] = (short)__builtin_bit_cast(unsigned short, vreg[i][j]);
                *(i16x4*)((char*)Vt + byte) = pk;
            }

            __syncthreads();   // tile fully staged

            // (3) compute (green read paths, single buffer)
            f32x4 s[4][2];
            #pragma unroll
            for (int nf = 0; nf < 4; nf++) {
                bf16x8 kf[2];
                #pragma unroll
                for (int kk = 0; kk < 2; kk++) {
                    const int row = nf * 16 + lr;
                    int byte = row * 128 + (kk * 32 + lg * 8) * 2;
                    byte ^= (row & 7) << 4;
                    kf[kk] = *(const bf16x8*)((const char*)Kt + byte);
                }
                #pragma unroll
                for (int rf = 0; rf < 2; rf++) {
                    f32x4 acc = {};
                    acc = __builtin_amdgcn_mfma_f32_16x16x32_bf16(kf[0], qf[rf][0], acc, 0, 0, 0);
                    acc = __builtin_amdgcn_mfma_f32_16x16x32_bf16(kf[1], qf[rf][1], acc, 0, 0, 0);
                    s[nf][rf] = acc;
                }
            }

            i16x4 pa[2][4];
            if (kv0 + 63 > qrow0) {
                #pragma unroll
                for (int rf = 0; rf < 2; rf++) {
                    const int qg = qrow0 + rf * 16 + lr;
                    #pragma unroll
                    for (int nf = 0; nf < 4; nf++)
                        #pragma unroll
                        for (int rr = 0; rr < 4; rr++) {
                            const int kvg = kv0 + nf * 16 + lg * 4 + rr;
                            float sv = s[nf][rf][rr];
                            sv = (kvg > qg) ? -1e30f : sv;
                            const float p = __builtin_amdgcn_exp2f(sv);
                            l_lane[rf] += p;
                            bf16 ph = (bf16)p;
                            pa[rf][nf][rr] = (short)__builtin_bit_cast(unsigned short, ph);
                        }
                }
            } else {
                #pragma unroll
                for (int rf = 0; rf < 2; rf++)
                    #pragma unroll
                    for (int nf = 0; nf < 4; nf++)
                        #pragma unroll
                        for (int rr = 0; rr < 4; rr++) {
                            const float p = __builtin_amdgcn_exp2f(s[nf][rf][rr]);
                            l_lane[rf] += p;
                            bf16 ph = (bf16)p;
                            pa[rf][nf][rr] = (short)__builtin_bit_cast(unsigned short, ph);
                        }
            }

            i16x4 vf[4][4];
            #pragma unroll
            for (int hf = 0; hf < 4; hf++)
                #pragma unroll
                for (int nf = 0; nf < 4; nf++) {
                    const int hd = hf * 16 + lr;
                    int byte = hd * 128 + (nf * 16 + lg * 4) * 2;
                    byte ^= (hd & 7) << 4;
                    vf[hf][nf] = *(const i16x4*)((const char*)Vt + byte);
                }

            __builtin_amdgcn_s_setprio(1);
            #pragma unroll
            for (int rf = 0; rf < 2; rf++)
                #pragma unroll
                for (int hf = 0; hf < 4; hf++)
                    #pragma unroll
                    for (int nf = 0; nf < 4; nf++)
                        mfma16(acc_o[rf][hf], pa[rf][nf], vf[hf][nf]);
            __builtin_amdgcn_s_setprio(0);
            // no trailing barrier: next iteration's barrier (after its global
            // loads) provides the read-complete guarantee
        }

        #pragma unroll
        for (int rf = 0; rf < 2; rf++) {
            float l = l_lane[rf];
            l += __shfl_xor(l, 16);
            l += __shfl_xor(l, 32);
            const float linv = 1.0f / l;
            #pragma unroll
            for (int rr = 0; rr < 4; rr++) {
                const float li = __shfl(linv, lg * 4 + rr, 16);
                const int row = qrow0 + rf * 16 + lg * 4 + rr;
                #pragma unroll
                for (int hf = 0; hf < 4; hf++) {
                    const int col = h * NHD + hf * 16 + lr;
                    Og[((size_t)b * NS + row) * ND + col] = (bf16)(acc_o[rf][hf][rr] * li);
                }
            }
        }
        __syncthreads();   // pass boundary: all LDS reads done before pass+1 stages
    }
}

// ---------------------------------------------------------------------------
// Compare: spins ~750us iff any |ob - ob2| > 1e-3. Duration = answer channel.
// ---------------------------------------------------------------------------
__global__ __launch_bounds__(256) void cmp_kern(const bf16* __restrict__ a,
                                                const bf16* __restrict__ b)
{
    const size_t n = (size_t)NM * ND;
    float md = 0.f;
    for (size_t i = (size_t)blockIdx.x * 256 + threadIdx.x; i < n; i += (size_t)256 * 1024)
        md = fmaxf(md, fabsf((float)a[i] - (float)b[i]));
    #pragma unroll
    for (int off = 1; off < 64; off <<= 1)
        md = fmaxf(md, __shfl_xor(md, off));
    if (md > 1e-3f) {
        float xx = md;
        for (int i = 0; i < 150000; i++)
            asm volatile("v_fma_f32 %0, %0, %1, %2" : "+v"(xx) : "v"(1.0000001f), "v"(1e-7f));
        asm volatile("" :: "v"(xx));   // keep live
    }
}

// ---------------------------------------------------------------------------
extern "C" void kernel_launch(void* const* d_in, const int* in_sizes, int n_in,
                              void* d_out, int out_size, void* d_ws, size_t ws_size,
                              hipStream_t stream) {
    const float* query = (const float*)d_in[0];
    const float* key   = (const float*)d_in[1];
    const float* value = (const float*)d_in[2];
    // d_in[3] = mask: causal tril by construction -> computed analytically
    const float* wq = (const float*)d_in[4];
    const float* bq = (const float*)d_in[5];
    const float* wk = (const float*)d_in[6];
    const float* bk = (const float*)d_in[7];
    const float* wv = (const float*)d_in[8];
    const float* bv = (const float*)d_in[9];
    const float* wo = (const float*)d_in[10];
    const float* bo = (const float*)d_in[11];
    float* out = (float*)d_out;

    bf16* qb  = (bf16*)d_ws;                       // (B,H,S,HD)
    bf16* kb  = qb + (size_t)NM * ND;
    bf16* vb  = kb + (size_t)NM * ND;
    bf16* ob  = vb + (size_t)NM * ND;              // (B,S,D)
    bf16* ob2 = ob + (size_t)NM * ND;              // shadow output

    const bool do_shadow = ws_size >= (size_t)5 * NM * ND * sizeof(bf16);

    gemm_proj3<<<dim3(NM / 128, ND / 128, 3), 256, 0, stream>>>(
            query, key, value, wq, wk, wv, bq, bk, bv, qb, kb, vb);

    attn_kern<<<dim3(NS / 64, NH, NB), 128, 0, stream>>>(qb, kb, vb, ob);

    if (do_shadow) {
        attn_v2<<<dim3(16, NH, NB), 128, 0, stream>>>(qb, kb, vb, ob2);
        cmp_kern<<<dim3(1024), 256, 0, stream>>>(ob, ob2);
    }

    gemm_out<<<dim3(NM / 128, ND / 128), 256, 0, stream>>>(ob, wo, bo, out);
}